// Round 1
// baseline (269.558 us; speedup 1.0000x reference)
//
#include <hip/hip_runtime.h>

#define NQ 10000
#define BS 2
#define NV 19560
#define NH 8
#define HD 32
#define EMB 256

typedef __attribute__((ext_vector_type(8))) short bf16x8;
typedef __attribute__((ext_vector_type(4))) float f32x4;
typedef __attribute__((ext_vector_type(4))) short s16x4;

__device__ __forceinline__ unsigned short f2bf(float x) {
    unsigned u = __float_as_uint(x);
    u += 0x7FFFu + ((u >> 16) & 1u);       // RNE
    return (unsigned short)(u >> 16);
}

// ---------------------------------------------------------------------------
// Transpose weights into Bt[n][k] bf16 (rows 0-255 W_val, 256-511 W_off,
// 512-639 W_attn) + concat biases. Tiny one-shot kernel. [proven]
// ---------------------------------------------------------------------------
__global__ __launch_bounds__(256) void convert_W(
    const float* __restrict__ Wv, const float* __restrict__ Wo,
    const float* __restrict__ Wa, const float* __restrict__ bv,
    const float* __restrict__ bo, const float* __restrict__ ba,
    ushort* __restrict__ Bt, float* __restrict__ bias) {
    int n = blockIdx.x;      // 0..639
    int k = threadIdx.x;     // 0..255
    float x;
    if (n < 256)       x = Wv[k * 256 + n];
    else if (n < 512)  x = Wo[k * 256 + (n - 256)];
    else               x = Wa[k * 128 + (n - 512)];
    Bt[n * 256 + k] = f2bf(x);
    if (k == 0)
        bias[n] = (n < 256) ? bv[n] : (n < 512) ? bo[n - 256] : ba[n - 512];
}

// ---------------------------------------------------------------------------
// Fused GEMM, one dispatch for both projections. ROUND-10 RESTRUCTURE:
// direct-to-fragment streaming GEMM — NO LDS, NO barriers.
// Each lane loads its MFMA A fragment straight from global (2x f32x4 per
// 16-row block, rows tile into full 128B spans per wave -> 100% line
// utilization, identical HBM efficiency to the old staging load), converts
// fp32->bf16 in registers (same f2bf, bit-identical numerics), and loads B
// fragments as bf16x8 from Bt (already [n][k] bf16). The K-loop (8 steps,
// fully unrolled) has no synchronization at all -> the old per-step
// vmcnt(0)-drain convoy (MfmaUtil 5%, VALUBusy 15%, 80% idle) disappears;
// the compiler pipelines loads across steps. B panel (<=64KB/block, 327KB
// total) is L2-hot; paired waves share A rows via L1.
// blockIdx < 1224: value-proj (mblk=bid>>1, npan=bid&1), planar bf16 store.
// Else: query-proj (A = query+query_pos summed in regs), fp32 off|attn.
// Epilogue mapping unchanged [proven].
// ---------------------------------------------------------------------------
__global__ __launch_bounds__(256) void gemm_fused(
    const float* __restrict__ value, const float* __restrict__ query,
    const float* __restrict__ qpos, const ushort* __restrict__ Bt,
    const float* __restrict__ bias,
    ushort* __restrict__ Cv, float* __restrict__ C0, float* __restrict__ C1)
{
    const int tid = threadIdx.x;
    const int bid = blockIdx.x;
    bool isval; int mblk, npan;
    if (bid < 1224) { isval = true;  mblk = bid >> 1; npan = bid & 1; }
    else { int q = bid - 1224; isval = false; mblk = q / 3; npan = q % 3; }

    const int M  = isval ? (BS * NV) : (BS * NQ);
    const int m0 = mblk * 64;
    const int n0 = npan * 128;
    const int nbase = (isval ? 0 : 256) + n0;

    const float* A = isval ? value : query;

    const int lane = tid & 63, wave = tid >> 6;
    const int wrow = (wave >> 1) * 32, wcol = (wave & 1) * 64;
    const int lr = lane & 15, quad = lane >> 4, lk = quad * 8;

    // Per-lane fragment base pointers. Rows past M are clamped to a valid
    // row (finite data, no NaN) — the epilogue guards all stores with gm<M,
    // so clamped rows' acc values are never written.
    const float* Ap[2]; const float* Qp[2];
    #pragma unroll
    for (int i = 0; i < 2; i++) {
        int row = m0 + wrow + i * 16 + lr;
        if (row >= M) row = M - 1;
        Ap[i] = A    + (size_t)row * 256 + lk;
        Qp[i] = qpos + (size_t)row * 256 + lk;
    }
    const ushort* Bp[4];
    #pragma unroll
    for (int j = 0; j < 4; j++)
        Bp[j] = Bt + (size_t)(nbase + wcol + j * 16 + lr) * 256 + lk;

    f32x4 acc[2][4] = {};

    #pragma unroll
    for (int k0 = 0; k0 < 256; k0 += 32) {
        bf16x8 bhf[4];
        #pragma unroll
        for (int j = 0; j < 4; j++)
            bhf[j] = *(const bf16x8*)(Bp[j] + k0);

        bf16x8 af[2];
        #pragma unroll
        for (int i = 0; i < 2; i++) {
            f32x4 lo = *(const f32x4*)(Ap[i] + k0);
            f32x4 hi = *(const f32x4*)(Ap[i] + k0 + 4);
            if (!isval) {
                lo += *(const f32x4*)(Qp[i] + k0);
                hi += *(const f32x4*)(Qp[i] + k0 + 4);
            }
            bf16x8 t;
            #pragma unroll
            for (int e = 0; e < 4; e++) {
                t[e]     = (short)f2bf(lo[e]);
                t[e + 4] = (short)f2bf(hi[e]);
            }
            af[i] = t;
        }

        #pragma unroll
        for (int i = 0; i < 2; i++)
            #pragma unroll
            for (int j = 0; j < 4; j++)
                acc[i][j] = __builtin_amdgcn_mfma_f32_16x16x32_bf16(af[i], bhf[j], acc[i][j], 0, 0, 0);
    }

    // ---- epilogue (proven mapping, unchanged) ----
    #pragma unroll
    for (int j = 0; j < 4; j++) {
        int cc = wcol + j * 16 + lr;
        int col = n0 + cc;
        float bb = bias[nbase + cc];
        #pragma unroll
        for (int i = 0; i < 2; i++) {
            int gmb = m0 + wrow + i * 16 + quad * 4;
            #pragma unroll
            for (int r = 0; r < 4; r++) {
                int gm = gmb + r;
                if (gm < M) {
                    float val = acc[i][j][r] + bb;
                    if (isval) {
                        int h = col >> 5, d = col & 31;
                        int b = (gm >= NV) ? 1 : 0;
                        int pix = gm - b * NV;
                        Cv[((size_t)(b * 8 + h) * NV + pix) * 32 + d] = f2bf(val);
                    } else {
                        if (col < 256) C0[(size_t)gm * 256 + col] = val;
                        else           C1[(size_t)gm * 128 + (col - 256)] = val;
                    }
                }
            }
        }
    }
}

// ---------------------------------------------------------------------------
// Fused softmax + location + bilinear gather. [round-7 PROVEN, verbatim]
// Block = TWO (b,q), 256 threads. Phase 1: softmax + coords + corner offsets
// + premultiplied weights -> LDS. Phase 2: 16 lanes per (q,h), lane = channel
// pair; 16-wide register load batches; 4 split accumulators.
// ---------------------------------------------------------------------------
__global__ __launch_bounds__(256) void sample4(
    const ushort* __restrict__ v, const float* __restrict__ off,
    const float* __restrict__ attn, const float* __restrict__ refp,
    float* __restrict__ out)
{
    __shared__ int   s_off[256][5];
    __shared__ float s_w[256][5];

    const int bq0 = blockIdx.x * 2;
    const int t = threadIdx.x;

    {
        const int bq = bq0 + (t >> 7);
        const int b = (bq >= NQ) ? 1 : 0;
        const int i = t & 127;
        const int h = i >> 4, l = (i >> 2) & 3, p = i & 3;

        float logit = attn[(size_t)bq * 128 + i];
        float mx = logit;
        #pragma unroll
        for (int m = 1; m < 16; m <<= 1) mx = fmaxf(mx, __shfl_xor(mx, m, 16));
        float e = __expf(logit - mx);
        float s = e;
        #pragma unroll
        for (int m = 1; m < 16; m <<= 1) s += __shfl_xor(s, m, 16);
        float w = e / s;

        const float Wf[4] = {160.f, 80.f, 40.f, 20.f};
        const float Hf[4] = {92.f, 46.f, 23.f, 12.f};
        const int   Wi[4] = {160, 80, 40, 20};
        const int   Hi[4] = {92, 46, 23, 12};
        const int   st[4] = {0, 14720, 18400, 19320};

        float ox = off[(size_t)bq * 256 + h * 32 + l * 8 + p * 2];
        float oy = off[(size_t)bq * 256 + h * 32 + l * 8 + p * 2 + 1];
        float rx = refp[(size_t)bq * 8 + p * 2];
        float ry = refp[(size_t)bq * 8 + p * 2 + 1];
        float x = rx * Wf[l] + ox - 0.5f;
        float y = ry * Hf[l] + oy - 0.5f;
        float x0f = floorf(x), y0f = floorf(y);
        float wx1 = x - x0f, wy1 = y - y0f;
        float wx0 = 1.f - wx1, wy0 = 1.f - wy1;
        int x0 = (int)x0f, y0 = (int)y0f;
        const int W = Wi[l], H = Hi[l];
        float mx0 = ((unsigned)x0       < (unsigned)W) ? 1.f : 0.f;
        float mx1 = ((unsigned)(x0 + 1) < (unsigned)W) ? 1.f : 0.f;
        float my0 = ((unsigned)y0       < (unsigned)H) ? 1.f : 0.f;
        float my1 = ((unsigned)(y0 + 1) < (unsigned)H) ? 1.f : 0.f;
        int xc0 = min(max(x0, 0), W - 1);
        int xc1 = min(max(x0 + 1, 0), W - 1);
        int yc0 = min(max(y0, 0), H - 1);
        int yc1 = min(max(y0 + 1, 0), H - 1);
        int base = ((b * 8 + h) * NV + st[l]) * 32;
        s_off[t][0] = base + (yc0 * W + xc0) * 32;
        s_off[t][1] = base + (yc0 * W + xc1) * 32;
        s_off[t][2] = base + (yc1 * W + xc0) * 32;
        s_off[t][3] = base + (yc1 * W + xc1) * 32;
        s_w[t][0] = w * wy0 * wx0 * my0 * mx0;
        s_w[t][1] = w * wy0 * wx1 * my0 * mx1;
        s_w[t][2] = w * wy1 * wx0 * my1 * mx0;
        s_w[t][3] = w * wy1 * wx1 * my1 * mx1;
    }
    __syncthreads();

    const int g = t >> 4;          // 0..15: (qi, h)
    const int lane = t & 15;       // channel pair
    const int qi = g >> 3, h = g & 7;
    const int bq = bq0 + qi;
    const int d2 = lane * 2;
    const int pbase = qi * 128 + h * 16;

    float acc0 = 0.f, acc1 = 0.f, acc2 = 0.f, acc3 = 0.f;
    #pragma unroll
    for (int ib = 0; ib < 4; ib++) {
        int o[16]; float wgt[16];
        #pragma unroll
        for (int pp = 0; pp < 4; pp++) {
            int idx = pbase + ib * 4 + pp;
            #pragma unroll
            for (int c = 0; c < 4; c++) {
                o[pp * 4 + c]   = s_off[idx][c];
                wgt[pp * 4 + c] = s_w[idx][c];
            }
        }
        unsigned u[16];
        #pragma unroll
        for (int j = 0; j < 16; j++)
            u[j] = *(const unsigned*)(v + o[j] + d2);
        #pragma unroll
        for (int j = 0; j < 16; j += 2) {
            acc0 += wgt[j]     * __uint_as_float(u[j] << 16);
            acc1 += wgt[j]     * __uint_as_float(u[j] & 0xffff0000u);
            acc2 += wgt[j + 1] * __uint_as_float(u[j + 1] << 16);
            acc3 += wgt[j + 1] * __uint_as_float(u[j + 1] & 0xffff0000u);
        }
    }
    float2 res = make_float2(acc0 + acc2, acc1 + acc3);
    *(float2*)(out + (size_t)bq * 256 + h * 32 + d2) = res;
}

extern "C" void kernel_launch(void* const* d_in, const int* in_sizes, int n_in,
                              void* d_out, int out_size, void* d_ws, size_t ws_size,
                              hipStream_t stream) {
    const float* query     = (const float*)d_in[0];
    const float* value     = (const float*)d_in[1];
    const float* query_pos = (const float*)d_in[2];
    const float* refp      = (const float*)d_in[3];
    const float* W_val     = (const float*)d_in[4];
    const float* b_val     = (const float*)d_in[5];
    const float* W_off     = (const float*)d_in[6];
    const float* b_off     = (const float*)d_in[7];
    const float* W_attn    = (const float*)d_in[8];
    const float* b_attn    = (const float*)d_in[9];
    float* out = (float*)d_out;

    char* w = (char*)d_ws;
    float*  off    = (float*)w;   w += 20480000;   // 20000 x 256 fp32
    float*  attn   = (float*)w;   w += 10240000;   // 20000 x 128 fp32
    ushort* vp_bf  = (ushort*)w;  w += 20029440;   // planar (b,h,NV,32) bf16
    ushort* Bt     = (ushort*)w;  w += 327680;     // 640 x 256 bf16
    float*  bias_c = (float*)w;   w += 2560;

    convert_W<<<640, 256, 0, stream>>>(W_val, W_off, W_attn, b_val, b_off, b_attn,
                                       Bt, bias_c);

    // one dispatch: value-proj (1224 blocks) + query-proj (939 blocks)
    gemm_fused<<<1224 + 939, 256, 0, stream>>>(value, query, query_pos, Bt, bias_c,
                                               vp_bf, off, attn);

    // fused softmax + loc + bilinear sample (2 queries per block)
    sample4<<<BS * NQ / 2, 256, 0, stream>>>(vp_bf, off, attn, refp, out);
}

// Round 2
// 248.876 us; speedup vs baseline: 1.0831x; 1.0831x over previous
//
#include <hip/hip_runtime.h>

#define NQ 10000
#define BS 2
#define NV 19560
#define NH 8
#define HD 32
#define EMB 256

typedef __attribute__((ext_vector_type(8))) short bf16x8;
typedef __attribute__((ext_vector_type(4))) float f32x4;
typedef __attribute__((ext_vector_type(4))) short s16x4;

__device__ __forceinline__ unsigned short f2bf(float x) {
    unsigned u = __float_as_uint(x);
    u += 0x7FFFu + ((u >> 16) & 1u);       // RNE
    return (unsigned short)(u >> 16);
}

// ---------------------------------------------------------------------------
// Transpose weights into Bt[n][k] bf16 (rows 0-255 W_val, 256-511 W_off,
// 512-639 W_attn) + concat biases. Tiny one-shot kernel. [proven]
// ---------------------------------------------------------------------------
__global__ __launch_bounds__(256) void convert_W(
    const float* __restrict__ Wv, const float* __restrict__ Wo,
    const float* __restrict__ Wa, const float* __restrict__ bv,
    const float* __restrict__ bo, const float* __restrict__ ba,
    ushort* __restrict__ Bt, float* __restrict__ bias) {
    int n = blockIdx.x;      // 0..639
    int k = threadIdx.x;     // 0..255
    float x;
    if (n < 256)       x = Wv[k * 256 + n];
    else if (n < 512)  x = Wo[k * 256 + (n - 256)];
    else               x = Wa[k * 128 + (n - 512)];
    Bt[n * 256 + k] = f2bf(x);
    if (k == 0)
        bias[n] = (n < 256) ? bv[n] : (n < 512) ? bo[n - 256] : ba[n - 512];
}

// ---------------------------------------------------------------------------
// Fused GEMM, one dispatch for both projections. ROUND-11 RESTRUCTURE:
// r10's direct-to-fragment failed (latency-bound: every load on the MFMA
// critical path, BW halved). This round restores LDS staging for A but
// kills r9's per-step convoy (8 MFMAs between 2 barriers):
//  - B (L2/L3-hot 320KB panel) preloaded ONCE into 32 bf16x8 regs/lane.
//  - A staged full-K (64x256 bf16) in LDS, in two K=128 halves; each half
//    = 8 independent f32x4 loads/thread issued back-to-back (deep vmcnt
//    pipeline, streaming pattern).
//  - 2 barriers TOTAL: stage(h0); bar; {issue h1 loads | MFMA s0..3 |
//    write h1}; bar; MFMA s4..7. 32 MFMAs/wave per phase hide h1 latency.
//  - LDS row stride 264 shorts = 33 granules (odd) -> bank-slot
//    (row+granule)%8 uniform for b128 reads AND writes -> ~0 conflicts.
// Epilogue mapping unchanged [proven].
// ---------------------------------------------------------------------------
__global__ __launch_bounds__(256) void gemm_fused(
    const float* __restrict__ value, const float* __restrict__ query,
    const float* __restrict__ qpos, const ushort* __restrict__ Bt,
    const float* __restrict__ bias,
    ushort* __restrict__ Cv, float* __restrict__ C0, float* __restrict__ C1)
{
    __shared__ __align__(16) short As[64][264];   // 33792 B

    const int tid = threadIdx.x;
    const int bid = blockIdx.x;
    bool isval; int mblk, npan;
    if (bid < 1224) { isval = true;  mblk = bid >> 1; npan = bid & 1; }
    else { int q = bid - 1224; isval = false; mblk = q / 3; npan = q % 3; }

    const int M  = isval ? (BS * NV) : (BS * NQ);
    const int m0 = mblk * 64;
    const int n0 = npan * 128;
    const int nbase = (isval ? 0 : 256) + n0;

    const int lane = tid & 63, wave = tid >> 6;
    const int wrow = (wave >> 1) * 32, wcol = (wave & 1) * 64;
    const int lr = lane & 15, quad = lane >> 4;

    // staging role: thread t -> A row t>>2 (0..63), k-chunk (t&3)*8; each
    // thread covers that chunk in all 8 k-steps (stride 32).
    const int trow = tid >> 2;
    const int tkc  = (tid & 3) * 8;
    int arow = m0 + trow; if (arow >= M) arow = M - 1;   // clamp; stores guarded
    const float* Ap = (isval ? value : query) + (size_t)arow * 256 + tkc;
    const float* Qp = qpos + (size_t)arow * 256 + tkc;

    // ---- B fragments: 32 bf16x8 held in registers for the whole kernel ----
    bf16x8 bfr[8][4];
    #pragma unroll
    for (int j = 0; j < 4; j++) {
        const ushort* bp = Bt + (size_t)(nbase + wcol + j * 16 + lr) * 256 + quad * 8;
        #pragma unroll
        for (int s = 0; s < 8; s++)
            bfr[s][j] = *(const bf16x8*)(bp + s * 32);
    }

    f32x4 acc[2][4] = {};

    // ---- stage half 0 (k = 0..127): 8 loads in flight, convert, write ----
    {
        f32x4 lo[4], hi[4];
        #pragma unroll
        for (int s = 0; s < 4; s++) {
            lo[s] = *(const f32x4*)(Ap + s * 32);
            hi[s] = *(const f32x4*)(Ap + s * 32 + 4);
        }
        if (!isval) {
            #pragma unroll
            for (int s = 0; s < 4; s++) {
                lo[s] += *(const f32x4*)(Qp + s * 32);
                hi[s] += *(const f32x4*)(Qp + s * 32 + 4);
            }
        }
        #pragma unroll
        for (int s = 0; s < 4; s++) {
            bf16x8 t;
            #pragma unroll
            for (int e = 0; e < 4; e++) {
                t[e]     = (short)f2bf(lo[s][e]);
                t[e + 4] = (short)f2bf(hi[s][e]);
            }
            *(bf16x8*)&As[trow][tkc + s * 32] = t;
        }
    }
    __syncthreads();

    // ---- phase 1: issue half-1 loads | MFMA steps 0..3 | write half 1 ----
    {
        f32x4 lo[4], hi[4];
        #pragma unroll
        for (int s = 0; s < 4; s++) {
            lo[s] = *(const f32x4*)(Ap + 128 + s * 32);
            hi[s] = *(const f32x4*)(Ap + 128 + s * 32 + 4);
        }
        if (!isval) {
            #pragma unroll
            for (int s = 0; s < 4; s++) {
                lo[s] += *(const f32x4*)(Qp + 128 + s * 32);
                hi[s] += *(const f32x4*)(Qp + 128 + s * 32 + 4);
            }
        }
        // MFMA on half 0 while half-1 loads are in flight
        #pragma unroll
        for (int s = 0; s < 4; s++) {
            bf16x8 af[2];
            #pragma unroll
            for (int i = 0; i < 2; i++)
                af[i] = *(const bf16x8*)&As[wrow + i * 16 + lr][s * 32 + quad * 8];
            #pragma unroll
            for (int i = 0; i < 2; i++)
                #pragma unroll
                for (int j = 0; j < 4; j++)
                    acc[i][j] = __builtin_amdgcn_mfma_f32_16x16x32_bf16(af[i], bfr[s][j], acc[i][j], 0, 0, 0);
        }
        // write half 1 (vmcnt waits land here, after the MFMA block)
        #pragma unroll
        for (int s = 0; s < 4; s++) {
            bf16x8 t;
            #pragma unroll
            for (int e = 0; e < 4; e++) {
                t[e]     = (short)f2bf(lo[s][e]);
                t[e + 4] = (short)f2bf(hi[s][e]);
            }
            *(bf16x8*)&As[trow][128 + tkc + s * 32] = t;
        }
    }
    __syncthreads();

    // ---- phase 2: MFMA steps 4..7 ----
    #pragma unroll
    for (int s = 4; s < 8; s++) {
        bf16x8 af[2];
        #pragma unroll
        for (int i = 0; i < 2; i++)
            af[i] = *(const bf16x8*)&As[wrow + i * 16 + lr][s * 32 + quad * 8];
        #pragma unroll
        for (int i = 0; i < 2; i++)
            #pragma unroll
            for (int j = 0; j < 4; j++)
                acc[i][j] = __builtin_amdgcn_mfma_f32_16x16x32_bf16(af[i], bfr[s][j], acc[i][j], 0, 0, 0);
    }

    // ---- epilogue (proven mapping, unchanged) ----
    #pragma unroll
    for (int j = 0; j < 4; j++) {
        int cc = wcol + j * 16 + lr;
        int col = n0 + cc;
        float bb = bias[nbase + cc];
        #pragma unroll
        for (int i = 0; i < 2; i++) {
            int gmb = m0 + wrow + i * 16 + quad * 4;
            #pragma unroll
            for (int r = 0; r < 4; r++) {
                int gm = gmb + r;
                if (gm < M) {
                    float val = acc[i][j][r] + bb;
                    if (isval) {
                        int h = col >> 5, d = col & 31;
                        int b = (gm >= NV) ? 1 : 0;
                        int pix = gm - b * NV;
                        Cv[((size_t)(b * 8 + h) * NV + pix) * 32 + d] = f2bf(val);
                    } else {
                        if (col < 256) C0[(size_t)gm * 256 + col] = val;
                        else           C1[(size_t)gm * 128 + (col - 256)] = val;
                    }
                }
            }
        }
    }
}

// ---------------------------------------------------------------------------
// Fused softmax + location + bilinear gather. [round-7 PROVEN, verbatim]
// Block = TWO (b,q), 256 threads. Phase 1: softmax + coords + corner offsets
// + premultiplied weights -> LDS. Phase 2: 16 lanes per (q,h), lane = channel
// pair; 16-wide register load batches; 4 split accumulators.
// ---------------------------------------------------------------------------
__global__ __launch_bounds__(256) void sample4(
    const ushort* __restrict__ v, const float* __restrict__ off,
    const float* __restrict__ attn, const float* __restrict__ refp,
    float* __restrict__ out)
{
    __shared__ int   s_off[256][5];
    __shared__ float s_w[256][5];

    const int bq0 = blockIdx.x * 2;
    const int t = threadIdx.x;

    {
        const int bq = bq0 + (t >> 7);
        const int b = (bq >= NQ) ? 1 : 0;
        const int i = t & 127;
        const int h = i >> 4, l = (i >> 2) & 3, p = i & 3;

        float logit = attn[(size_t)bq * 128 + i];
        float mx = logit;
        #pragma unroll
        for (int m = 1; m < 16; m <<= 1) mx = fmaxf(mx, __shfl_xor(mx, m, 16));
        float e = __expf(logit - mx);
        float s = e;
        #pragma unroll
        for (int m = 1; m < 16; m <<= 1) s += __shfl_xor(s, m, 16);
        float w = e / s;

        const float Wf[4] = {160.f, 80.f, 40.f, 20.f};
        const float Hf[4] = {92.f, 46.f, 23.f, 12.f};
        const int   Wi[4] = {160, 80, 40, 20};
        const int   Hi[4] = {92, 46, 23, 12};
        const int   st[4] = {0, 14720, 18400, 19320};

        float ox = off[(size_t)bq * 256 + h * 32 + l * 8 + p * 2];
        float oy = off[(size_t)bq * 256 + h * 32 + l * 8 + p * 2 + 1];
        float rx = refp[(size_t)bq * 8 + p * 2];
        float ry = refp[(size_t)bq * 8 + p * 2 + 1];
        float x = rx * Wf[l] + ox - 0.5f;
        float y = ry * Hf[l] + oy - 0.5f;
        float x0f = floorf(x), y0f = floorf(y);
        float wx1 = x - x0f, wy1 = y - y0f;
        float wx0 = 1.f - wx1, wy0 = 1.f - wy1;
        int x0 = (int)x0f, y0 = (int)y0f;
        const int W = Wi[l], H = Hi[l];
        float mx0 = ((unsigned)x0       < (unsigned)W) ? 1.f : 0.f;
        float mx1 = ((unsigned)(x0 + 1) < (unsigned)W) ? 1.f : 0.f;
        float my0 = ((unsigned)y0       < (unsigned)H) ? 1.f : 0.f;
        float my1 = ((unsigned)(y0 + 1) < (unsigned)H) ? 1.f : 0.f;
        int xc0 = min(max(x0, 0), W - 1);
        int xc1 = min(max(x0 + 1, 0), W - 1);
        int yc0 = min(max(y0, 0), H - 1);
        int yc1 = min(max(y0 + 1, 0), H - 1);
        int base = ((b * 8 + h) * NV + st[l]) * 32;
        s_off[t][0] = base + (yc0 * W + xc0) * 32;
        s_off[t][1] = base + (yc0 * W + xc1) * 32;
        s_off[t][2] = base + (yc1 * W + xc0) * 32;
        s_off[t][3] = base + (yc1 * W + xc1) * 32;
        s_w[t][0] = w * wy0 * wx0 * my0 * mx0;
        s_w[t][1] = w * wy0 * wx1 * my0 * mx1;
        s_w[t][2] = w * wy1 * wx0 * my1 * mx0;
        s_w[t][3] = w * wy1 * wx1 * my1 * mx1;
    }
    __syncthreads();

    const int g = t >> 4;          // 0..15: (qi, h)
    const int lane = t & 15;       // channel pair
    const int qi = g >> 3, h = g & 7;
    const int bq = bq0 + qi;
    const int d2 = lane * 2;
    const int pbase = qi * 128 + h * 16;

    float acc0 = 0.f, acc1 = 0.f, acc2 = 0.f, acc3 = 0.f;
    #pragma unroll
    for (int ib = 0; ib < 4; ib++) {
        int o[16]; float wgt[16];
        #pragma unroll
        for (int pp = 0; pp < 4; pp++) {
            int idx = pbase + ib * 4 + pp;
            #pragma unroll
            for (int c = 0; c < 4; c++) {
                o[pp * 4 + c]   = s_off[idx][c];
                wgt[pp * 4 + c] = s_w[idx][c];
            }
        }
        unsigned u[16];
        #pragma unroll
        for (int j = 0; j < 16; j++)
            u[j] = *(const unsigned*)(v + o[j] + d2);
        #pragma unroll
        for (int j = 0; j < 16; j += 2) {
            acc0 += wgt[j]     * __uint_as_float(u[j] << 16);
            acc1 += wgt[j]     * __uint_as_float(u[j] & 0xffff0000u);
            acc2 += wgt[j + 1] * __uint_as_float(u[j + 1] << 16);
            acc3 += wgt[j + 1] * __uint_as_float(u[j + 1] & 0xffff0000u);
        }
    }
    float2 res = make_float2(acc0 + acc2, acc1 + acc3);
    *(float2*)(out + (size_t)bq * 256 + h * 32 + d2) = res;
}

extern "C" void kernel_launch(void* const* d_in, const int* in_sizes, int n_in,
                              void* d_out, int out_size, void* d_ws, size_t ws_size,
                              hipStream_t stream) {
    const float* query     = (const float*)d_in[0];
    const float* value     = (const float*)d_in[1];
    const float* query_pos = (const float*)d_in[2];
    const float* refp      = (const float*)d_in[3];
    const float* W_val     = (const float*)d_in[4];
    const float* b_val     = (const float*)d_in[5];
    const float* W_off     = (const float*)d_in[6];
    const float* b_off     = (const float*)d_in[7];
    const float* W_attn    = (const float*)d_in[8];
    const float* b_attn    = (const float*)d_in[9];
    float* out = (float*)d_out;

    char* w = (char*)d_ws;
    float*  off    = (float*)w;   w += 20480000;   // 20000 x 256 fp32
    float*  attn   = (float*)w;   w += 10240000;   // 20000 x 128 fp32
    ushort* vp_bf  = (ushort*)w;  w += 20029440;   // planar (b,h,NV,32) bf16
    ushort* Bt     = (ushort*)w;  w += 327680;     // 640 x 256 bf16
    float*  bias_c = (float*)w;   w += 2560;

    convert_W<<<640, 256, 0, stream>>>(W_val, W_off, W_attn, b_val, b_off, b_attn,
                                       Bt, bias_c);

    // one dispatch: value-proj (1224 blocks) + query-proj (939 blocks)
    gemm_fused<<<1224 + 939, 256, 0, stream>>>(value, query, query_pos, Bt, bias_c,
                                               vp_bf, off, attn);

    // fused softmax + loc + bilinear sample (2 queries per block)
    sample4<<<BS * NQ / 2, 256, 0, stream>>>(vp_bf, off, attn, refp, out);
}

// Round 3
// 221.924 us; speedup vs baseline: 1.2146x; 1.1214x over previous
//
#include <hip/hip_runtime.h>

#define NQ 10000
#define BS 2
#define NV 19560
#define NH 8
#define HD 32
#define EMB 256

typedef __attribute__((ext_vector_type(8))) short bf16x8;
typedef __attribute__((ext_vector_type(4))) float f32x4;
typedef __attribute__((ext_vector_type(4))) short s16x4;

__device__ __forceinline__ unsigned short f2bf(float x) {
    unsigned u = __float_as_uint(x);
    u += 0x7FFFu + ((u >> 16) & 1u);       // RNE
    return (unsigned short)(u >> 16);
}

// ---------------------------------------------------------------------------
// Transpose weights into Bt[n][k] bf16 (rows 0-255 W_val, 256-511 W_off,
// 512-639 W_attn) + concat biases. Tiny one-shot kernel. [proven]
// ---------------------------------------------------------------------------
__global__ __launch_bounds__(256) void convert_W(
    const float* __restrict__ Wv, const float* __restrict__ Wo,
    const float* __restrict__ Wa, const float* __restrict__ bv,
    const float* __restrict__ bo, const float* __restrict__ ba,
    ushort* __restrict__ Bt, float* __restrict__ bias) {
    int n = blockIdx.x;      // 0..639
    int k = threadIdx.x;     // 0..255
    float x;
    if (n < 256)       x = Wv[k * 256 + n];
    else if (n < 512)  x = Wo[k * 256 + (n - 256)];
    else               x = Wa[k * 128 + (n - 512)];
    Bt[n * 256 + k] = f2bf(x);
    if (k == 0)
        bias[n] = (n < 256) ? bv[n] : (n < 512) ? bo[n - 256] : ba[n - 512];
}

// ---------------------------------------------------------------------------
// Fused GEMM. ROUND-12: r9 (61us, proven-best) with ONE structural change —
// the 2x __syncthreads per k-step (each lowered with a full vmcnt(0) drain,
// the m97 barrier-drain stall) is replaced by:
//   - LDS double-buffer (As[2], Bhs[2]; same 40-short padded layout),
//   - register prefetch of step k+1's A/B global loads, issued BEFORE the
//     MFMA phase of step k so they fly during ds_read+MFMA,
//   - ONE raw s_barrier per step with only lgkmcnt(0) (T3/T4-lite: loads
//     stay in flight across the barrier; vmcnt waits land naturally at the
//     convert that consumes the prefetch regs, AFTER the MFMAs).
// Race audit: RAW (writes buf[nxt] -> lgkmcnt(0) -> barrier -> read) OK;
// WAR (buf[nxt] last read step s-1 before that step's end barrier) OK;
// reg prefetch is private, no fencing needed. Tile/roles/epilogue verbatim
// from r9 [proven]. r10/r11 restructures are abandoned (both regressed).
// ---------------------------------------------------------------------------
__global__ __launch_bounds__(256) void gemm_fused(
    const float* __restrict__ value, const float* __restrict__ query,
    const float* __restrict__ qpos, const ushort* __restrict__ Bt,
    const float* __restrict__ bias,
    ushort* __restrict__ Cv, float* __restrict__ C0, float* __restrict__ C1)
{
    __shared__ __align__(16) short As[2][64][40];
    __shared__ __align__(16) short Bhs[2][128][40];   // 30720 B total

    const int tid = threadIdx.x;
    const int bid = blockIdx.x;
    bool isval; int mblk, npan;
    if (bid < 1224) { isval = true;  mblk = bid >> 1; npan = bid & 1; }
    else { int q = bid - 1224; isval = false; mblk = q / 3; npan = q % 3; }

    const int M  = isval ? (BS * NV) : (BS * NQ);
    const int m0 = mblk * 64;
    const int n0 = npan * 128;
    const int nbase = (isval ? 0 : 256) + n0;

    const float* A = isval ? value : query;

    // A staging: thread t -> row t>>2 (0..63), k-chunk (t&3)*8 (8 of 32 k)
    const int arow = tid >> 2;
    const int acol = (tid & 3) * 8;
    const bool aval = (m0 + arow) < M;
    const float* Ap  = A    + (size_t)(m0 + arow) * 256 + acol;
    const float* A2p = qpos + (size_t)(m0 + arow) * 256 + acol;
    // B staging: thread t -> row t>>1 (0..127), k-half (t&1)*16 (16 of 32 k)
    const int brow = tid >> 1;
    const int bcol = (tid & 1) * 16;
    const ushort* Bp = Bt + (size_t)(nbase + brow) * 256 + bcol;

    const int lane = tid & 63, wave = tid >> 6;
    const int wrow = (wave >> 1) * 32, wcol = (wave & 1) * 64;
    const int lr = lane & 15, quad = lane >> 4, lk = quad * 8;

    f32x4 acc[2][4] = {};

    // ---- prologue: stage step 0 into buffer 0 (r9 staging, verbatim) ----
    {
        #pragma unroll
        for (int g = 0; g < 2; g++) {
            f32x4 v = {};
            if (aval) {
                v = *(const f32x4*)(Ap + g * 4);
                if (!isval) v += *(const f32x4*)(A2p + g * 4);
            }
            s16x4 hh;
            #pragma unroll
            for (int e = 0; e < 4; e++) hh[e] = (short)f2bf(v[e]);
            *(s16x4*)&As[0][arow][acol + g * 4] = hh;
        }
        *(bf16x8*)&Bhs[0][brow][bcol]     = *(const bf16x8*)(Bp);
        *(bf16x8*)&Bhs[0][brow][bcol + 8] = *(const bf16x8*)(Bp + 8);
    }
    asm volatile("s_waitcnt lgkmcnt(0)" ::: "memory");
    __builtin_amdgcn_s_barrier();

    #pragma unroll
    for (int s = 0; s < 8; s++) {
        const int cur = s & 1, nxt = cur ^ 1;
        const int k1 = (s + 1) * 32;

        // ---- issue step s+1 loads into registers (fly during MFMA) ----
        f32x4 pa0 = {}, pa1 = {}, qa0 = {}, qa1 = {};
        bf16x8 pb0, pb1;
        if (s < 7) {
            if (aval) {
                pa0 = *(const f32x4*)(Ap + k1);
                pa1 = *(const f32x4*)(Ap + k1 + 4);
                if (!isval) {
                    qa0 = *(const f32x4*)(A2p + k1);
                    qa1 = *(const f32x4*)(A2p + k1 + 4);
                }
            }
            pb0 = *(const bf16x8*)(Bp + k1);
            pb1 = *(const bf16x8*)(Bp + k1 + 8);
        }

        // ---- compute phase on buf[cur] ----
        bf16x8 af[2], bhf[4];
        #pragma unroll
        for (int i = 0; i < 2; i++)
            af[i] = *(const bf16x8*)&As[cur][wrow + i * 16 + lr][lk];
        #pragma unroll
        for (int j = 0; j < 4; j++)
            bhf[j] = *(const bf16x8*)&Bhs[cur][wcol + j * 16 + lr][lk];
        #pragma unroll
        for (int i = 0; i < 2; i++)
            #pragma unroll
            for (int j = 0; j < 4; j++)
                acc[i][j] = __builtin_amdgcn_mfma_f32_16x16x32_bf16(af[i], bhf[j], acc[i][j], 0, 0, 0);

        // ---- convert + write step s+1 into buf[nxt] (vmcnt waits here) ----
        if (s < 7) {
            if (!isval) { pa0 += qa0; pa1 += qa1; }
            bf16x8 t;
            #pragma unroll
            for (int e = 0; e < 4; e++) {
                t[e]     = (short)f2bf(pa0[e]);
                t[e + 4] = (short)f2bf(pa1[e]);
            }
            *(bf16x8*)&As[nxt][arow][acol & ~7] = t;   // acol is multiple of 8? no: (t&3)*8 -> yes, 0/8/16/24
            *(bf16x8*)&Bhs[nxt][brow][bcol]     = pb0;
            *(bf16x8*)&Bhs[nxt][brow][bcol + 8] = pb1;

            asm volatile("s_waitcnt lgkmcnt(0)" ::: "memory");
            __builtin_amdgcn_s_barrier();
        }
    }

    // ---- epilogue (proven mapping, unchanged) ----
    #pragma unroll
    for (int j = 0; j < 4; j++) {
        int cc = wcol + j * 16 + lr;
        int col = n0 + cc;
        float bb = bias[nbase + cc];
        #pragma unroll
        for (int i = 0; i < 2; i++) {
            int gmb = m0 + wrow + i * 16 + quad * 4;
            #pragma unroll
            for (int r = 0; r < 4; r++) {
                int gm = gmb + r;
                if (gm < M) {
                    float val = acc[i][j][r] + bb;
                    if (isval) {
                        int h = col >> 5, d = col & 31;
                        int b = (gm >= NV) ? 1 : 0;
                        int pix = gm - b * NV;
                        Cv[((size_t)(b * 8 + h) * NV + pix) * 32 + d] = f2bf(val);
                    } else {
                        if (col < 256) C0[(size_t)gm * 256 + col] = val;
                        else           C1[(size_t)gm * 128 + (col - 256)] = val;
                    }
                }
            }
        }
    }
}

// ---------------------------------------------------------------------------
// Fused softmax + location + bilinear gather. [round-7 PROVEN, verbatim]
// ---------------------------------------------------------------------------
__global__ __launch_bounds__(256) void sample4(
    const ushort* __restrict__ v, const float* __restrict__ off,
    const float* __restrict__ attn, const float* __restrict__ refp,
    float* __restrict__ out)
{
    __shared__ int   s_off[256][5];
    __shared__ float s_w[256][5];

    const int bq0 = blockIdx.x * 2;
    const int t = threadIdx.x;

    {
        const int bq = bq0 + (t >> 7);
        const int b = (bq >= NQ) ? 1 : 0;
        const int i = t & 127;
        const int h = i >> 4, l = (i >> 2) & 3, p = i & 3;

        float logit = attn[(size_t)bq * 128 + i];
        float mx = logit;
        #pragma unroll
        for (int m = 1; m < 16; m <<= 1) mx = fmaxf(mx, __shfl_xor(mx, m, 16));
        float e = __expf(logit - mx);
        float s = e;
        #pragma unroll
        for (int m = 1; m < 16; m <<= 1) s += __shfl_xor(s, m, 16);
        float w = e / s;

        const float Wf[4] = {160.f, 80.f, 40.f, 20.f};
        const float Hf[4] = {92.f, 46.f, 23.f, 12.f};
        const int   Wi[4] = {160, 80, 40, 20};
        const int   Hi[4] = {92, 46, 23, 12};
        const int   st[4] = {0, 14720, 18400, 19320};

        float ox = off[(size_t)bq * 256 + h * 32 + l * 8 + p * 2];
        float oy = off[(size_t)bq * 256 + h * 32 + l * 8 + p * 2 + 1];
        float rx = refp[(size_t)bq * 8 + p * 2];
        float ry = refp[(size_t)bq * 8 + p * 2 + 1];
        float x = rx * Wf[l] + ox - 0.5f;
        float y = ry * Hf[l] + oy - 0.5f;
        float x0f = floorf(x), y0f = floorf(y);
        float wx1 = x - x0f, wy1 = y - y0f;
        float wx0 = 1.f - wx1, wy0 = 1.f - wy1;
        int x0 = (int)x0f, y0 = (int)y0f;
        const int W = Wi[l], H = Hi[l];
        float mx0 = ((unsigned)x0       < (unsigned)W) ? 1.f : 0.f;
        float mx1 = ((unsigned)(x0 + 1) < (unsigned)W) ? 1.f : 0.f;
        float my0 = ((unsigned)y0       < (unsigned)H) ? 1.f : 0.f;
        float my1 = ((unsigned)(y0 + 1) < (unsigned)H) ? 1.f : 0.f;
        int xc0 = min(max(x0, 0), W - 1);
        int xc1 = min(max(x0 + 1, 0), W - 1);
        int yc0 = min(max(y0, 0), H - 1);
        int yc1 = min(max(y0 + 1, 0), H - 1);
        int base = ((b * 8 + h) * NV + st[l]) * 32;
        s_off[t][0] = base + (yc0 * W + xc0) * 32;
        s_off[t][1] = base + (yc0 * W + xc1) * 32;
        s_off[t][2] = base + (yc1 * W + xc0) * 32;
        s_off[t][3] = base + (yc1 * W + xc1) * 32;
        s_w[t][0] = w * wy0 * wx0 * my0 * mx0;
        s_w[t][1] = w * wy0 * wx1 * my0 * mx1;
        s_w[t][2] = w * wy1 * wx0 * my1 * mx0;
        s_w[t][3] = w * wy1 * wx1 * my1 * mx1;
    }
    __syncthreads();

    const int g = t >> 4;          // 0..15: (qi, h)
    const int lane = t & 15;       // channel pair
    const int qi = g >> 3, h = g & 7;
    const int bq = bq0 + qi;
    const int d2 = lane * 2;
    const int pbase = qi * 128 + h * 16;

    float acc0 = 0.f, acc1 = 0.f, acc2 = 0.f, acc3 = 0.f;
    #pragma unroll
    for (int ib = 0; ib < 4; ib++) {
        int o[16]; float wgt[16];
        #pragma unroll
        for (int pp = 0; pp < 4; pp++) {
            int idx = pbase + ib * 4 + pp;
            #pragma unroll
            for (int c = 0; c < 4; c++) {
                o[pp * 4 + c]   = s_off[idx][c];
                wgt[pp * 4 + c] = s_w[idx][c];
            }
        }
        unsigned u[16];
        #pragma unroll
        for (int j = 0; j < 16; j++)
            u[j] = *(const unsigned*)(v + o[j] + d2);
        #pragma unroll
        for (int j = 0; j < 16; j += 2) {
            acc0 += wgt[j]     * __uint_as_float(u[j] << 16);
            acc1 += wgt[j]     * __uint_as_float(u[j] & 0xffff0000u);
            acc2 += wgt[j + 1] * __uint_as_float(u[j + 1] << 16);
            acc3 += wgt[j + 1] * __uint_as_float(u[j + 1] & 0xffff0000u);
        }
    }
    float2 res = make_float2(acc0 + acc2, acc1 + acc3);
    *(float2*)(out + (size_t)bq * 256 + h * 32 + d2) = res;
}

extern "C" void kernel_launch(void* const* d_in, const int* in_sizes, int n_in,
                              void* d_out, int out_size, void* d_ws, size_t ws_size,
                              hipStream_t stream) {
    const float* query     = (const float*)d_in[0];
    const float* value     = (const float*)d_in[1];
    const float* query_pos = (const float*)d_in[2];
    const float* refp      = (const float*)d_in[3];
    const float* W_val     = (const float*)d_in[4];
    const float* b_val     = (const float*)d_in[5];
    const float* W_off     = (const float*)d_in[6];
    const float* b_off     = (const float*)d_in[7];
    const float* W_attn    = (const float*)d_in[8];
    const float* b_attn    = (const float*)d_in[9];
    float* out = (float*)d_out;

    char* w = (char*)d_ws;
    float*  off    = (float*)w;   w += 20480000;   // 20000 x 256 fp32
    float*  attn   = (float*)w;   w += 10240000;   // 20000 x 128 fp32
    ushort* vp_bf  = (ushort*)w;  w += 20029440;   // planar (b,h,NV,32) bf16
    ushort* Bt     = (ushort*)w;  w += 327680;     // 640 x 256 bf16
    float*  bias_c = (float*)w;   w += 2560;

    convert_W<<<640, 256, 0, stream>>>(W_val, W_off, W_attn, b_val, b_off, b_attn,
                                       Bt, bias_c);

    // one dispatch: value-proj (1224 blocks) + query-proj (939 blocks)
    gemm_fused<<<1224 + 939, 256, 0, stream>>>(value, query, query_pos, Bt, bias_c,
                                               vp_bf, off, attn);

    // fused softmax + loc + bilinear sample (2 queries per block)
    sample4<<<BS * NQ / 2, 256, 0, stream>>>(vp_bf, off, attn, refp, out);
}

// Round 4
// 214.312 us; speedup vs baseline: 1.2578x; 1.0355x over previous
//
#include <hip/hip_runtime.h>

#define NQ 10000
#define BS 2
#define NV 19560
#define NH 8
#define HD 32
#define EMB 256

typedef __attribute__((ext_vector_type(8))) short bf16x8;
typedef __attribute__((ext_vector_type(4))) float f32x4;
typedef __attribute__((ext_vector_type(4))) short s16x4;

__device__ __forceinline__ unsigned short f2bf(float x) {
    unsigned u = __float_as_uint(x);
    u += 0x7FFFu + ((u >> 16) & 1u);       // RNE
    return (unsigned short)(u >> 16);
}

// ---------------------------------------------------------------------------
// Transpose weights into Bt[n][k] bf16 (rows 0-255 W_val, 256-511 W_off,
// 512-639 W_attn) + concat biases. Tiny one-shot kernel. [proven]
// ---------------------------------------------------------------------------
__global__ __launch_bounds__(256) void convert_W(
    const float* __restrict__ Wv, const float* __restrict__ Wo,
    const float* __restrict__ Wa, const float* __restrict__ bv,
    const float* __restrict__ bo, const float* __restrict__ ba,
    ushort* __restrict__ Bt, float* __restrict__ bias) {
    int n = blockIdx.x;      // 0..639
    int k = threadIdx.x;     // 0..255
    float x;
    if (n < 256)       x = Wv[k * 256 + n];
    else if (n < 512)  x = Wo[k * 256 + (n - 256)];
    else               x = Wa[k * 128 + (n - 512)];
    Bt[n * 256 + k] = f2bf(x);
    if (k == 0)
        bias[n] = (n < 256) ? bv[n] : (n < 512) ? bo[n - 256] : ba[n - 512];
}

// ---------------------------------------------------------------------------
// Fused GEMM. ROUND-13: exact r9 body (61us proven; r10/r11/r12 restructures
// all regressed -> k-loop sync structure is NOT the limiter) + ONE isolated
// change: T1 XCD-aware bijective block remap (m204 form, per grid section).
// Mechanism: default round-robin puts the npan-PAIR (same 64 A-rows) and the
// query TRIOS on different XCD L2s -> value/query/qpos fetched 2-3x from HBM
// (FETCH 101MB vs 81 ideal). Chunked remap co-locates each pair/trio + ~150
// consecutive blocks per XCD: A re-reads become L2 hits (~200cyc vs ~900).
// val section: 1224 = 8*153 exact. query section: 939 = 8*117+3, m204 split.
// ---------------------------------------------------------------------------
__global__ __launch_bounds__(256) void gemm_fused(
    const float* __restrict__ value, const float* __restrict__ query,
    const float* __restrict__ qpos, const ushort* __restrict__ Bt,
    const float* __restrict__ bias,
    ushort* __restrict__ Cv, float* __restrict__ C0, float* __restrict__ C1)
{
    __shared__ short As[64][40], Bhs[128][40];  // pad 32->40

    const int tid = threadIdx.x;

    // ---- T1: XCD-aware bijective remap (only change vs r9) ----
    const int bid0 = blockIdx.x;
    int bid;
    if (bid0 < 1224) {
        bid = (bid0 & 7) * 153 + (bid0 >> 3);              // 1224 = 8*153
    } else {
        int q = bid0 - 1224;                               // 939 = 8*117+3
        int xcd = q & 7, idx = q >> 3;
        int orig = (xcd < 3) ? (xcd * 118 + idx)
                             : (3 * 118 + (xcd - 3) * 117 + idx);
        bid = 1224 + orig;
    }

    bool isval; int mblk, npan;
    if (bid < 1224) { isval = true;  mblk = bid >> 1; npan = bid & 1; }
    else { int q = bid - 1224; isval = false; mblk = q / 3; npan = q % 3; }

    const int M  = isval ? (BS * NV) : (BS * NQ);
    const int m0 = mblk * 64;
    const int n0 = npan * 128;
    const int nbase = (isval ? 0 : 256) + n0;

    const float* A = isval ? value : query;

    // A staging: thread t -> row t>>2 (0..63), k-chunk (t&3)*8 (8 of 32 k)
    const int arow = tid >> 2;
    const int acol = (tid & 3) * 8;
    const bool aval = (m0 + arow) < M;
    const float* Ap  = A    + (size_t)(m0 + arow) * 256 + acol;
    const float* A2p = qpos + (size_t)(m0 + arow) * 256 + acol;
    // B staging: thread t -> row t>>1 (0..127), k-half (t&1)*16 (16 of 32 k)
    const int brow = tid >> 1;
    const int bcol = (tid & 1) * 16;
    const ushort* Bp = Bt + (size_t)(nbase + brow) * 256 + bcol;

    const int lane = tid & 63, wave = tid >> 6;
    const int wrow = (wave >> 1) * 32, wcol = (wave & 1) * 64;
    const int lr = lane & 15, quad = lane >> 4, lk = quad * 8;

    f32x4 acc[2][4] = {};

    for (int k0 = 0; k0 < 256; k0 += 32) {
        // ---- A: fp32 (+qpos) -> bf16 staged to LDS (proven form) ----
        #pragma unroll
        for (int g = 0; g < 2; g++) {
            f32x4 v = {};
            if (aval) {
                v = *(const f32x4*)(Ap + k0 + g * 4);
                if (!isval) v += *(const f32x4*)(A2p + k0 + g * 4);
            }
            s16x4 hh;
            #pragma unroll
            for (int e = 0; e < 4; e++) hh[e] = (short)f2bf(v[e]);
            *(s16x4*)&As[arow][acol + g * 4] = hh;
        }
        // ---- B: bf16 vector copy, BOTH halves (16 shorts/thread) ----
        *(bf16x8*)&Bhs[brow][bcol]     = *(const bf16x8*)(Bp + k0);
        *(bf16x8*)&Bhs[brow][bcol + 8] = *(const bf16x8*)(Bp + k0 + 8);
        __syncthreads();

        bf16x8 af[2], bhf[4];
        #pragma unroll
        for (int i = 0; i < 2; i++)
            af[i] = *(const bf16x8*)&As[wrow + i * 16 + lr][lk];
        #pragma unroll
        for (int j = 0; j < 4; j++)
            bhf[j] = *(const bf16x8*)&Bhs[wcol + j * 16 + lr][lk];
        #pragma unroll
        for (int i = 0; i < 2; i++)
            #pragma unroll
            for (int j = 0; j < 4; j++)
                acc[i][j] = __builtin_amdgcn_mfma_f32_16x16x32_bf16(af[i], bhf[j], acc[i][j], 0, 0, 0);
        __syncthreads();
    }

    // ---- epilogue (proven mapping) ----
    #pragma unroll
    for (int j = 0; j < 4; j++) {
        int cc = wcol + j * 16 + lr;
        int col = n0 + cc;
        float bb = bias[nbase + cc];
        #pragma unroll
        for (int i = 0; i < 2; i++) {
            int gmb = m0 + wrow + i * 16 + quad * 4;
            #pragma unroll
            for (int r = 0; r < 4; r++) {
                int gm = gmb + r;
                if (gm < M) {
                    float val = acc[i][j][r] + bb;
                    if (isval) {
                        int h = col >> 5, d = col & 31;
                        int b = (gm >= NV) ? 1 : 0;
                        int pix = gm - b * NV;
                        Cv[((size_t)(b * 8 + h) * NV + pix) * 32 + d] = f2bf(val);
                    } else {
                        if (col < 256) C0[(size_t)gm * 256 + col] = val;
                        else           C1[(size_t)gm * 128 + (col - 256)] = val;
                    }
                }
            }
        }
    }
}

// ---------------------------------------------------------------------------
// Fused softmax + location + bilinear gather. [round-7 PROVEN, verbatim]
// Block = TWO (b,q), 256 threads. Phase 1: softmax + coords + corner offsets
// + premultiplied weights -> LDS. Phase 2: 16 lanes per (q,h), lane = channel
// pair; 16-wide register load batches; 4 split accumulators.
// ---------------------------------------------------------------------------
__global__ __launch_bounds__(256) void sample4(
    const ushort* __restrict__ v, const float* __restrict__ off,
    const float* __restrict__ attn, const float* __restrict__ refp,
    float* __restrict__ out)
{
    __shared__ int   s_off[256][5];
    __shared__ float s_w[256][5];

    const int bq0 = blockIdx.x * 2;
    const int t = threadIdx.x;

    {
        const int bq = bq0 + (t >> 7);
        const int b = (bq >= NQ) ? 1 : 0;
        const int i = t & 127;
        const int h = i >> 4, l = (i >> 2) & 3, p = i & 3;

        float logit = attn[(size_t)bq * 128 + i];
        float mx = logit;
        #pragma unroll
        for (int m = 1; m < 16; m <<= 1) mx = fmaxf(mx, __shfl_xor(mx, m, 16));
        float e = __expf(logit - mx);
        float s = e;
        #pragma unroll
        for (int m = 1; m < 16; m <<= 1) s += __shfl_xor(s, m, 16);
        float w = e / s;

        const float Wf[4] = {160.f, 80.f, 40.f, 20.f};
        const float Hf[4] = {92.f, 46.f, 23.f, 12.f};
        const int   Wi[4] = {160, 80, 40, 20};
        const int   Hi[4] = {92, 46, 23, 12};
        const int   st[4] = {0, 14720, 18400, 19320};

        float ox = off[(size_t)bq * 256 + h * 32 + l * 8 + p * 2];
        float oy = off[(size_t)bq * 256 + h * 32 + l * 8 + p * 2 + 1];
        float rx = refp[(size_t)bq * 8 + p * 2];
        float ry = refp[(size_t)bq * 8 + p * 2 + 1];
        float x = rx * Wf[l] + ox - 0.5f;
        float y = ry * Hf[l] + oy - 0.5f;
        float x0f = floorf(x), y0f = floorf(y);
        float wx1 = x - x0f, wy1 = y - y0f;
        float wx0 = 1.f - wx1, wy0 = 1.f - wy1;
        int x0 = (int)x0f, y0 = (int)y0f;
        const int W = Wi[l], H = Hi[l];
        float mx0 = ((unsigned)x0       < (unsigned)W) ? 1.f : 0.f;
        float mx1 = ((unsigned)(x0 + 1) < (unsigned)W) ? 1.f : 0.f;
        float my0 = ((unsigned)y0       < (unsigned)H) ? 1.f : 0.f;
        float my1 = ((unsigned)(y0 + 1) < (unsigned)H) ? 1.f : 0.f;
        int xc0 = min(max(x0, 0), W - 1);
        int xc1 = min(max(x0 + 1, 0), W - 1);
        int yc0 = min(max(y0, 0), H - 1);
        int yc1 = min(max(y0 + 1, 0), H - 1);
        int base = ((b * 8 + h) * NV + st[l]) * 32;
        s_off[t][0] = base + (yc0 * W + xc0) * 32;
        s_off[t][1] = base + (yc0 * W + xc1) * 32;
        s_off[t][2] = base + (yc1 * W + xc0) * 32;
        s_off[t][3] = base + (yc1 * W + xc1) * 32;
        s_w[t][0] = w * wy0 * wx0 * my0 * mx0;
        s_w[t][1] = w * wy0 * wx1 * my0 * mx1;
        s_w[t][2] = w * wy1 * wx0 * my1 * mx0;
        s_w[t][3] = w * wy1 * wx1 * my1 * mx1;
    }
    __syncthreads();

    const int g = t >> 4;          // 0..15: (qi, h)
    const int lane = t & 15;       // channel pair
    const int qi = g >> 3, h = g & 7;
    const int bq = bq0 + qi;
    const int d2 = lane * 2;
    const int pbase = qi * 128 + h * 16;

    float acc0 = 0.f, acc1 = 0.f, acc2 = 0.f, acc3 = 0.f;
    #pragma unroll
    for (int ib = 0; ib < 4; ib++) {
        int o[16]; float wgt[16];
        #pragma unroll
        for (int pp = 0; pp < 4; pp++) {
            int idx = pbase + ib * 4 + pp;
            #pragma unroll
            for (int c = 0; c < 4; c++) {
                o[pp * 4 + c]   = s_off[idx][c];
                wgt[pp * 4 + c] = s_w[idx][c];
            }
        }
        unsigned u[16];
        #pragma unroll
        for (int j = 0; j < 16; j++)
            u[j] = *(const unsigned*)(v + o[j] + d2);
        #pragma unroll
        for (int j = 0; j < 16; j += 2) {
            acc0 += wgt[j]     * __uint_as_float(u[j] << 16);
            acc1 += wgt[j]     * __uint_as_float(u[j] & 0xffff0000u);
            acc2 += wgt[j + 1] * __uint_as_float(u[j + 1] << 16);
            acc3 += wgt[j + 1] * __uint_as_float(u[j + 1] & 0xffff0000u);
        }
    }
    float2 res = make_float2(acc0 + acc2, acc1 + acc3);
    *(float2*)(out + (size_t)bq * 256 + h * 32 + d2) = res;
}

extern "C" void kernel_launch(void* const* d_in, const int* in_sizes, int n_in,
                              void* d_out, int out_size, void* d_ws, size_t ws_size,
                              hipStream_t stream) {
    const float* query     = (const float*)d_in[0];
    const float* value     = (const float*)d_in[1];
    const float* query_pos = (const float*)d_in[2];
    const float* refp      = (const float*)d_in[3];
    const float* W_val     = (const float*)d_in[4];
    const float* b_val     = (const float*)d_in[5];
    const float* W_off     = (const float*)d_in[6];
    const float* b_off     = (const float*)d_in[7];
    const float* W_attn    = (const float*)d_in[8];
    const float* b_attn    = (const float*)d_in[9];
    float* out = (float*)d_out;

    char* w = (char*)d_ws;
    float*  off    = (float*)w;   w += 20480000;   // 20000 x 256 fp32
    float*  attn   = (float*)w;   w += 10240000;   // 20000 x 128 fp32
    ushort* vp_bf  = (ushort*)w;  w += 20029440;   // planar (b,h,NV,32) bf16
    ushort* Bt     = (ushort*)w;  w += 327680;     // 640 x 256 bf16
    float*  bias_c = (float*)w;   w += 2560;

    convert_W<<<640, 256, 0, stream>>>(W_val, W_off, W_attn, b_val, b_off, b_attn,
                                       Bt, bias_c);

    // one dispatch: value-proj (1224 blocks) + query-proj (939 blocks)
    gemm_fused<<<1224 + 939, 256, 0, stream>>>(value, query, query_pos, Bt, bias_c,
                                               vp_bf, off, attn);

    // fused softmax + loc + bilinear sample (2 queries per block)
    sample4<<<BS * NQ / 2, 256, 0, stream>>>(vp_bf, off, attn, refp, out);
}

// Round 5
// 202.236 us; speedup vs baseline: 1.3329x; 1.0597x over previous
//
#include <hip/hip_runtime.h>

#define NQ 10000
#define BS 2
#define NV 19560
#define NH 8
#define HD 32
#define EMB 256

typedef __attribute__((ext_vector_type(8))) short bf16x8;
typedef __attribute__((ext_vector_type(4))) float f32x4;
typedef __attribute__((ext_vector_type(4))) short s16x4;

__device__ __forceinline__ unsigned short f2bf(float x) {
    unsigned u = __float_as_uint(x);
    u += 0x7FFFu + ((u >> 16) & 1u);       // RNE
    return (unsigned short)(u >> 16);
}

// ---------------------------------------------------------------------------
// Transpose weights into Bt[n][k] bf16 (rows 0-255 W_val, 256-511 W_off,
// 512-639 W_attn) + concat biases. Tiny one-shot kernel. [proven]
// ---------------------------------------------------------------------------
__global__ __launch_bounds__(256) void convert_W(
    const float* __restrict__ Wv, const float* __restrict__ Wo,
    const float* __restrict__ Wa, const float* __restrict__ bv,
    const float* __restrict__ bo, const float* __restrict__ ba,
    ushort* __restrict__ Bt, float* __restrict__ bias) {
    int n = blockIdx.x;      // 0..639
    int k = threadIdx.x;     // 0..255
    float x;
    if (n < 256)       x = Wv[k * 256 + n];
    else if (n < 512)  x = Wo[k * 256 + (n - 256)];
    else               x = Wa[k * 128 + (n - 512)];
    Bt[n * 256 + k] = f2bf(x);
    if (k == 0)
        bias[n] = (n < 256) ? bv[n] : (n < 512) ? bo[n - 256] : ba[n - 512];
}

// ---------------------------------------------------------------------------
// Fused GEMM. [r13 PROVEN, verbatim: r9 body + T1 XCD bijective remap.
// FETCH 101->42MB confirmed; now latency-bound at small-GEMM floor.]
// ---------------------------------------------------------------------------
__global__ __launch_bounds__(256) void gemm_fused(
    const float* __restrict__ value, const float* __restrict__ query,
    const float* __restrict__ qpos, const ushort* __restrict__ Bt,
    const float* __restrict__ bias,
    ushort* __restrict__ Cv, float* __restrict__ C0, float* __restrict__ C1)
{
    __shared__ short As[64][40], Bhs[128][40];  // pad 32->40

    const int tid = threadIdx.x;

    // ---- T1: XCD-aware bijective remap [r13 proven] ----
    const int bid0 = blockIdx.x;
    int bid;
    if (bid0 < 1224) {
        bid = (bid0 & 7) * 153 + (bid0 >> 3);              // 1224 = 8*153
    } else {
        int q = bid0 - 1224;                               // 939 = 8*117+3
        int xcd = q & 7, idx = q >> 3;
        int orig = (xcd < 3) ? (xcd * 118 + idx)
                             : (3 * 118 + (xcd - 3) * 117 + idx);
        bid = 1224 + orig;
    }

    bool isval; int mblk, npan;
    if (bid < 1224) { isval = true;  mblk = bid >> 1; npan = bid & 1; }
    else { int q = bid - 1224; isval = false; mblk = q / 3; npan = q % 3; }

    const int M  = isval ? (BS * NV) : (BS * NQ);
    const int m0 = mblk * 64;
    const int n0 = npan * 128;
    const int nbase = (isval ? 0 : 256) + n0;

    const float* A = isval ? value : query;

    // A staging: thread t -> row t>>2 (0..63), k-chunk (t&3)*8 (8 of 32 k)
    const int arow = tid >> 2;
    const int acol = (tid & 3) * 8;
    const bool aval = (m0 + arow) < M;
    const float* Ap  = A    + (size_t)(m0 + arow) * 256 + acol;
    const float* A2p = qpos + (size_t)(m0 + arow) * 256 + acol;
    // B staging: thread t -> row t>>1 (0..127), k-half (t&1)*16 (16 of 32 k)
    const int brow = tid >> 1;
    const int bcol = (tid & 1) * 16;
    const ushort* Bp = Bt + (size_t)(nbase + brow) * 256 + bcol;

    const int lane = tid & 63, wave = tid >> 6;
    const int wrow = (wave >> 1) * 32, wcol = (wave & 1) * 64;
    const int lr = lane & 15, quad = lane >> 4, lk = quad * 8;

    f32x4 acc[2][4] = {};

    for (int k0 = 0; k0 < 256; k0 += 32) {
        // ---- A: fp32 (+qpos) -> bf16 staged to LDS (proven form) ----
        #pragma unroll
        for (int g = 0; g < 2; g++) {
            f32x4 v = {};
            if (aval) {
                v = *(const f32x4*)(Ap + k0 + g * 4);
                if (!isval) v += *(const f32x4*)(A2p + k0 + g * 4);
            }
            s16x4 hh;
            #pragma unroll
            for (int e = 0; e < 4; e++) hh[e] = (short)f2bf(v[e]);
            *(s16x4*)&As[arow][acol + g * 4] = hh;
        }
        // ---- B: bf16 vector copy, BOTH halves (16 shorts/thread) ----
        *(bf16x8*)&Bhs[brow][bcol]     = *(const bf16x8*)(Bp + k0);
        *(bf16x8*)&Bhs[brow][bcol + 8] = *(const bf16x8*)(Bp + k0 + 8);
        __syncthreads();

        bf16x8 af[2], bhf[4];
        #pragma unroll
        for (int i = 0; i < 2; i++)
            af[i] = *(const bf16x8*)&As[wrow + i * 16 + lr][lk];
        #pragma unroll
        for (int j = 0; j < 4; j++)
            bhf[j] = *(const bf16x8*)&Bhs[wcol + j * 16 + lr][lk];
        #pragma unroll
        for (int i = 0; i < 2; i++)
            #pragma unroll
            for (int j = 0; j < 4; j++)
                acc[i][j] = __builtin_amdgcn_mfma_f32_16x16x32_bf16(af[i], bhf[j], acc[i][j], 0, 0, 0);
        __syncthreads();
    }

    // ---- epilogue (proven mapping) ----
    #pragma unroll
    for (int j = 0; j < 4; j++) {
        int cc = wcol + j * 16 + lr;
        int col = n0 + cc;
        float bb = bias[nbase + cc];
        #pragma unroll
        for (int i = 0; i < 2; i++) {
            int gmb = m0 + wrow + i * 16 + quad * 4;
            #pragma unroll
            for (int r = 0; r < 4; r++) {
                int gm = gmb + r;
                if (gm < M) {
                    float val = acc[i][j][r] + bb;
                    if (isval) {
                        int h = col >> 5, d = col & 31;
                        int b = (gm >= NV) ? 1 : 0;
                        int pix = gm - b * NV;
                        Cv[((size_t)(b * 8 + h) * NV + pix) * 32 + d] = f2bf(val);
                    } else {
                        if (col < 256) C0[(size_t)gm * 256 + col] = val;
                        else           C1[(size_t)gm * 128 + (col - 256)] = val;
                    }
                }
            }
        }
    }
}

// ---------------------------------------------------------------------------
// Fused softmax + location + bilinear gather. ROUND-14 RESHAPE:
// block = 16 queries x ONE head (was 2 queries x 8 heads). One head's value
// plane = NV*64B = 1.25MB -> fits a 4MB XCD L2. (b,head) combo is encoded in
// blockIdx low 4 bits, so round-robin dispatch (bid%8 -> XCD, T1 basis) pins
// each combo's 625 blocks to one XCD; each XCD serves 2 combos = 2.5MB of
// value from L2 instead of scattering gathers over the whole 20MB buffer
// (r13 counters: FETCH 157MB, the dominant HBM term). Softmax is per-(q,h)
// over 16 (l,p) -> identical 16-lane shuffle reduce. Phase-2 accumulation
// structure verbatim; only the (group -> q,h) mapping changed.
// ---------------------------------------------------------------------------
__global__ __launch_bounds__(256) void sample4(
    const ushort* __restrict__ v, const float* __restrict__ off,
    const float* __restrict__ attn, const float* __restrict__ refp,
    float* __restrict__ out)
{
    __shared__ int   s_off[256][5];
    __shared__ float s_w[256][5];

    const int t = threadIdx.x;
    const int combo = blockIdx.x & 15;     // (b, head) -> fixed XCD slot
    const int qgrp  = blockIdx.x >> 4;     // 0..624
    const int b  = combo & 1;
    const int h0 = combo >> 1;             // 0..7

    {
        const int qloc = t >> 4;           // 0..15
        const int lp   = t & 15;
        const int l = lp >> 2, p = lp & 3;
        const size_t bq = (size_t)b * NQ + qgrp * 16 + qloc;

        float logit = attn[bq * 128 + h0 * 16 + lp];
        float mx = logit;
        #pragma unroll
        for (int m = 1; m < 16; m <<= 1) mx = fmaxf(mx, __shfl_xor(mx, m, 16));
        float e = __expf(logit - mx);
        float s = e;
        #pragma unroll
        for (int m = 1; m < 16; m <<= 1) s += __shfl_xor(s, m, 16);
        float w = e / s;

        const float Wf[4] = {160.f, 80.f, 40.f, 20.f};
        const float Hf[4] = {92.f, 46.f, 23.f, 12.f};
        const int   Wi[4] = {160, 80, 40, 20};
        const int   Hi[4] = {92, 46, 23, 12};
        const int   st[4] = {0, 14720, 18400, 19320};

        float ox = off[bq * 256 + h0 * 32 + l * 8 + p * 2];
        float oy = off[bq * 256 + h0 * 32 + l * 8 + p * 2 + 1];
        float rx = refp[bq * 8 + p * 2];
        float ry = refp[bq * 8 + p * 2 + 1];
        float x = rx * Wf[l] + ox - 0.5f;
        float y = ry * Hf[l] + oy - 0.5f;
        float x0f = floorf(x), y0f = floorf(y);
        float wx1 = x - x0f, wy1 = y - y0f;
        float wx0 = 1.f - wx1, wy0 = 1.f - wy1;
        int x0 = (int)x0f, y0 = (int)y0f;
        const int W = Wi[l], H = Hi[l];
        float mx0 = ((unsigned)x0       < (unsigned)W) ? 1.f : 0.f;
        float mx1 = ((unsigned)(x0 + 1) < (unsigned)W) ? 1.f : 0.f;
        float my0 = ((unsigned)y0       < (unsigned)H) ? 1.f : 0.f;
        float my1 = ((unsigned)(y0 + 1) < (unsigned)H) ? 1.f : 0.f;
        int xc0 = min(max(x0, 0), W - 1);
        int xc1 = min(max(x0 + 1, 0), W - 1);
        int yc0 = min(max(y0, 0), H - 1);
        int yc1 = min(max(y0 + 1, 0), H - 1);
        int base = ((b * 8 + h0) * NV + st[l]) * 32;
        s_off[t][0] = base + (yc0 * W + xc0) * 32;
        s_off[t][1] = base + (yc0 * W + xc1) * 32;
        s_off[t][2] = base + (yc1 * W + xc0) * 32;
        s_off[t][3] = base + (yc1 * W + xc1) * 32;
        s_w[t][0] = w * wy0 * wx0 * my0 * mx0;
        s_w[t][1] = w * wy0 * wx1 * my0 * mx1;
        s_w[t][2] = w * wy1 * wx0 * my1 * mx0;
        s_w[t][3] = w * wy1 * wx1 * my1 * mx1;
    }
    __syncthreads();

    const int g = t >> 4;          // 0..15: qloc
    const int lane = t & 15;       // channel pair
    const size_t bq = (size_t)b * NQ + qgrp * 16 + g;
    const int d2 = lane * 2;
    const int pbase = g * 16;      // 16 points of this (q, h0)

    float acc0 = 0.f, acc1 = 0.f, acc2 = 0.f, acc3 = 0.f;
    #pragma unroll
    for (int ib = 0; ib < 4; ib++) {
        int o[16]; float wgt[16];
        #pragma unroll
        for (int pp = 0; pp < 4; pp++) {
            int idx = pbase + ib * 4 + pp;
            #pragma unroll
            for (int c = 0; c < 4; c++) {
                o[pp * 4 + c]   = s_off[idx][c];
                wgt[pp * 4 + c] = s_w[idx][c];
            }
        }
        unsigned u[16];
        #pragma unroll
        for (int j = 0; j < 16; j++)
            u[j] = *(const unsigned*)(v + o[j] + d2);
        #pragma unroll
        for (int j = 0; j < 16; j += 2) {
            acc0 += wgt[j]     * __uint_as_float(u[j] << 16);
            acc1 += wgt[j]     * __uint_as_float(u[j] & 0xffff0000u);
            acc2 += wgt[j + 1] * __uint_as_float(u[j + 1] << 16);
            acc3 += wgt[j + 1] * __uint_as_float(u[j + 1] & 0xffff0000u);
        }
    }
    float2 res = make_float2(acc0 + acc2, acc1 + acc3);
    *(float2*)(out + bq * 256 + h0 * 32 + d2) = res;
}

extern "C" void kernel_launch(void* const* d_in, const int* in_sizes, int n_in,
                              void* d_out, int out_size, void* d_ws, size_t ws_size,
                              hipStream_t stream) {
    const float* query     = (const float*)d_in[0];
    const float* value     = (const float*)d_in[1];
    const float* query_pos = (const float*)d_in[2];
    const float* refp      = (const float*)d_in[3];
    const float* W_val     = (const float*)d_in[4];
    const float* b_val     = (const float*)d_in[5];
    const float* W_off     = (const float*)d_in[6];
    const float* b_off     = (const float*)d_in[7];
    const float* W_attn    = (const float*)d_in[8];
    const float* b_attn    = (const float*)d_in[9];
    float* out = (float*)d_out;

    char* w = (char*)d_ws;
    float*  off    = (float*)w;   w += 20480000;   // 20000 x 256 fp32
    float*  attn   = (float*)w;   w += 10240000;   // 20000 x 128 fp32
    ushort* vp_bf  = (ushort*)w;  w += 20029440;   // planar (b,h,NV,32) bf16
    ushort* Bt     = (ushort*)w;  w += 327680;     // 640 x 256 bf16
    float*  bias_c = (float*)w;   w += 2560;

    convert_W<<<640, 256, 0, stream>>>(W_val, W_off, W_attn, b_val, b_off, b_attn,
                                       Bt, bias_c);

    // one dispatch: value-proj (1224 blocks) + query-proj (939 blocks)
    gemm_fused<<<1224 + 939, 256, 0, stream>>>(value, query, query_pos, Bt, bias_c,
                                               vp_bf, off, attn);

    // fused softmax + loc + bilinear sample: 16 queries x 1 head per block,
    // (b,h) in low 4 bits of blockIdx -> XCD-local value plane (1.25MB in L2)
    sample4<<<(BS * NQ / 16) * NH, 256, 0, stream>>>(vp_bf, off, attn, refp, out);
}